// Round 29
// baseline (75.489 us; speedup 1.0000x reference)
//
#include <hip/hip_runtime.h>

typedef short bf16x8 __attribute__((ext_vector_type(8)));   // 8 bf16 = 4 VGPRs
typedef float f32x16 __attribute__((ext_vector_type(16)));  // MFMA 32x32 acc
typedef float f32x4  __attribute__((ext_vector_type(4)));

constexpr int B  = 16;
constexpr int H  = 128;
constexpr int CL = 2048;
constexpr int QL = 256;
constexpr int SPLITK5 = 4;
constexpr int K5SEG = CL / SPLITK5;   // 512
constexpr int PSTR = K5SEG + 8;       // 520 shorts = 260 dwords === 4 mod 32
constexpr float SHIFT = 8.0f;         // exp shift (overflow-safe, |s| ~ O(6))

__device__ __forceinline__ unsigned short f2bf(float x) {
  unsigned u = __float_as_uint(x);
  u += 0x7fffu + ((u >> 16) & 1u);   // round-to-nearest-even
  return (unsigned short)(u >> 16);
}
__device__ __forceinline__ float bf2f(unsigned short u) {
  return __uint_as_float((unsigned)u << 16);
}

// ---------------- KT: fp32 -> bf16 linear + transposed copies + bias partials ----
// ctx path additionally writes output group 0 (exact fp32 copy, NT stores).
template<int L, bool SCALE, bool WOUT>
__device__ __forceinline__ void ktrans_body(
    const float* __restrict__ src, const float* __restrict__ wbias,
    const float* __restrict__ wscale,
    unsigned short* __restrict__ dlin, unsigned short* __restrict__ dT,
    float* __restrict__ pbias, float* __restrict__ outg0,
    int bxl, int h1, int b, int tid,
    unsigned short (*T)[72], float (*P)[64]) {
  const int c0 = bxl * 64;
  const int hh = tid >> 4;
  const int cc4 = (tid & 15) * 4;
  float4 part = make_float4(0.f, 0.f, 0.f, 0.f);
  #pragma unroll
  for (int it = 0; it < 4; ++it) {
    const int hrow = it * 16 + hh;
    const int h = h1 * 64 + hrow;
    float4 v = *(const float4*)&src[((size_t)b * H + h) * L + c0 + cc4];
    const float wb = wbias[h];
    part.x = fmaf(v.x, wb, part.x); part.y = fmaf(v.y, wb, part.y);
    part.z = fmaf(v.z, wb, part.z); part.w = fmaf(v.w, wb, part.w);
    if (WOUT) {
      f32x4 t;
      t[0] = v.x; t[1] = v.y; t[2] = v.z; t[3] = v.w;
      __builtin_nontemporal_store(
          t, (f32x4*)&outg0[((size_t)b * 4 * H + h) * (size_t)CL + c0 + cc4]);
    }
    ushort4 o;
    o.x = f2bf(v.x); o.y = f2bf(v.y); o.z = f2bf(v.z); o.w = f2bf(v.w);
    *(ushort4*)&dlin[((size_t)b * H + h) * L + c0 + cc4] = o;
    ushort4 ot;
    if (SCALE) {
      const float ws = wscale[h];
      ot.x = f2bf(v.x * ws); ot.y = f2bf(v.y * ws);
      ot.z = f2bf(v.z * ws); ot.w = f2bf(v.w * ws);
    } else {
      ot = o;
    }
    *(ushort4*)&T[hrow][cc4] = ot;
  }
  *(float4*)&P[hh][cc4] = part;
  __syncthreads();
  if (tid < 64) {
    float sum = 0.f;
    #pragma unroll
    for (int i = 0; i < 16; ++i) sum += P[i][tid];
    pbias[(size_t)h1 * B * L + (size_t)b * L + c0 + tid] = sum;
  }
  #pragma unroll
  for (int it = 0; it < 4; ++it) {
    int lin = it * 256 + tid;
    int c = lin >> 4, hc = (lin & 15) * 4;
    ushort4 o;
    o.x = T[hc + 0][c]; o.y = T[hc + 1][c];
    o.z = T[hc + 2][c]; o.w = T[hc + 3][c];
    *(ushort4*)&dT[((size_t)b * L + c0 + c) * H + h1 * 64 + hc] = o;
  }
}

__global__ __launch_bounds__(256) void ktrans_all(
    const float* __restrict__ ctx, const float* __restrict__ qry,
    const float* __restrict__ w,
    unsigned short* __restrict__ ctx_bf, unsigned short* __restrict__ ctxwT,
    unsigned short* __restrict__ qry_bf, unsigned short* __restrict__ qryT,
    float* __restrict__ pct, float* __restrict__ pqt,
    float* __restrict__ out) {
  __shared__ unsigned short T[64][72];
  __shared__ float P[16][64];
  const int h1 = blockIdx.y, b = blockIdx.z, tid = threadIdx.x;
  const int bx = blockIdx.x;
  if (bx < CL / 64) {
    ktrans_body<CL, true, true>(ctx, w + H, w + 2 * H, ctx_bf, ctxwT, pct, out,
                                bx, h1, b, tid, T, P);
  } else {
    ktrans_body<QL, false, false>(qry, w, w, qry_bf, qryT, pqt, nullptr,
                                  bx - CL / 64, h1, b, tid, T, P);
  }
}

// ---------------- K5F: recompute score + cmask exp -> LDS P; t-MFMA + Lpart ----
// grid 1D = (QL/32)*SPLITK5*B, b innermost. block 256.
__global__ __launch_bounds__(256) void k5_fused(
    const unsigned short* __restrict__ ctxwT, const unsigned short* __restrict__ qryT,
    const unsigned short* __restrict__ ctxbf,
    const float* __restrict__ pct, const float* __restrict__ pqt,
    const int* __restrict__ cmask,
    unsigned short* __restrict__ tpart, float* __restrict__ Lpart) {
  __shared__ unsigned short P[32 * PSTR];  // [32 q][520 c], c XOR-swizzled per q-oct
  const int wg = blockIdx.x;
  const int b = wg & (B - 1);
  const int seg = (wg >> 4) & (SPLITK5 - 1);
  const int q0 = (wg >> 6) * 32;
  const int cseg = seg * K5SEG;
  const int tid = threadIdx.x;
  const int w = tid >> 6, l = tid & 63;
  const int lr = l & 31, hi = l >> 5;

  // A-frags: qryT rows q0+lr (shared across all four c-tiles)
  const unsigned short* ap = qryT + ((size_t)b * QL + q0 + lr) * H + hi * 8;
  bf16x8 afr[8];
  #pragma unroll
  for (int k = 0; k < 8; ++k) afr[k] = *(const bf16x8*)(ap + k * 16);

  #pragma unroll
  for (int t4 = 0; t4 < 4; ++t4) {
    const int cl = w * 128 + t4 * 32 + lr;  // local c in [0,512)
    const int c = cseg + cl;
    const unsigned short* bp = ctxwT + ((size_t)b * CL + c) * H + hi * 8;
    f32x16 acc = {};
    #pragma unroll
    for (int k = 0; k < 8; ++k) {
      bf16x8 bfr = *(const bf16x8*)(bp + k * 16);
      acc = __builtin_amdgcn_mfma_f32_32x32x16_bf16(afr[k], bfr, acc, 0, 0, 0);
    }
    const float ct = pct[b * CL + c] + pct[B * CL + b * CL + c];
    const bool cm = cmask[b * CL + c] > 0;
    #pragma unroll
    for (int g = 0; g < 4; ++g) {
      const int ql = 4 * hi + 8 * g;        // local q row
      const int qbase = q0 + ql;
      float4 qa = *(const float4*)&pqt[b * QL + qbase];
      float4 qb = *(const float4*)&pqt[B * QL + b * QL + qbase];
      const int key = (g & 3) << 3;         // ((ql>>3)&3)<<3
      const int cs = cl ^ key;
      P[(ql + 0) * PSTR + cs] = f2bf(cm ? __expf(acc[4*g+0] + ct + qa.x + qb.x - SHIFT) : 0.f);
      P[(ql + 1) * PSTR + cs] = f2bf(cm ? __expf(acc[4*g+1] + ct + qa.y + qb.y - SHIFT) : 0.f);
      P[(ql + 2) * PSTR + cs] = f2bf(cm ? __expf(acc[4*g+2] + ct + qa.z + qb.z - SHIFT) : 0.f);
      P[(ql + 3) * PSTR + cs] = f2bf(cm ? __expf(acc[4*g+3] + ct + qa.w + qb.w - SHIFT) : 0.f);
    }
  }
  __syncthreads();

  // t phase: wave w owns h-tile w. A = P rows (q=lr, swizzled), B = ctx_bf rows h.
  // Groups of 4 kc: issue 8 frags, fence (sched_barrier), then 4 MFMAs (setprio).
  const int h0 = w * 32;
  const unsigned short* bp2 = ctxbf + ((size_t)b * H + h0 + lr) * CL + cseg + hi * 8;
  const int rkey = ((lr >> 3) & 3) << 3;
  f32x16 acc = {};
  #pragma unroll
  for (int kg = 0; kg < 8; ++kg) {
    bf16x8 av[4], bv[4];
    #pragma unroll
    for (int j = 0; j < 4; ++j) {
      const int kc = kg * 4 + j;
      av[j] = *(const bf16x8*)&P[lr * PSTR + ((kc * 16 + hi * 8) ^ rkey)];
      bv[j] = *(const bf16x8*)(bp2 + kc * 16);
    }
    __builtin_amdgcn_sched_barrier(0);   // keep all 8 loads issued before MFMAs
    __builtin_amdgcn_s_setprio(1);
    #pragma unroll
    for (int j = 0; j < 4; ++j)
      acc = __builtin_amdgcn_mfma_f32_32x32x16_bf16(av[j], bv[j], acc, 0, 0, 0);
    __builtin_amdgcn_s_setprio(0);
  }
  unsigned short* tp = tpart + (size_t)(seg * B + b) * QL * H;
  #pragma unroll
  for (int r = 0; r < 16; ++r) {
    int qrow = (r & 3) + 8 * (r >> 2) + 4 * hi;
    tp[(size_t)(q0 + qrow) * H + h0 + lr] = f2bf(acc[r]);
  }

  // Lpart: per-q row sums of P (swizzle is a within-row bijection; sum invariant)
  {
    const int ql = tid >> 3, j = tid & 7;
    const unsigned short* pr = &P[ql * PSTR + j * 64];
    float s = 0.f;
    #pragma unroll
    for (int k = 0; k < 8; ++k) {
      bf16x8 v = *(const bf16x8*)(pr + k * 8);
      #pragma unroll
      for (int i = 0; i < 8; ++i) s += bf2f((unsigned short)v[i]);
    }
    s += __shfl_xor(s, 1);
    s += __shfl_xor(s, 2);
    s += __shfl_xor(s, 4);
    if (j == 0) Lpart[((size_t)b * SPLITK5 + seg) * QL + q0 + ql] = s;
  }
}

// ---------------- K5b: cinv from Lpart + reduce tpart, write tT_bf[b][h][q] ----
// grid (QL/64, H/16, B) = 512 blocks.
__global__ __launch_bounds__(256) void k5b_treduce(
    const unsigned short* __restrict__ tpart, const float* __restrict__ Lpart,
    unsigned short* __restrict__ tTbf) {
  __shared__ unsigned short lds[16 * 66];
  __shared__ float cinv_s[64];
  const int q0 = blockIdx.x * 64, h0 = blockIdx.y * 16, b = blockIdx.z;
  const int tid = threadIdx.x;
  if (tid < 64) {
    float Ls = 0.f;
    #pragma unroll
    for (int s = 0; s < SPLITK5; ++s)
      Ls += Lpart[((size_t)b * SPLITK5 + s) * QL + q0 + tid];
    cinv_s[tid] = 1.0f / Ls;
  }
  __syncthreads();
  for (int lin = tid; lin < 64 * 16; lin += 256) {
    int q = lin >> 4, h = lin & 15;
    float v = 0.f;
    #pragma unroll
    for (int sgt = 0; sgt < SPLITK5; ++sgt)
      v += bf2f(tpart[((size_t)(sgt * B + b) * QL + q0 + q) * H + h0 + h]);
    lds[h * 66 + q] = f2bf(v * cinv_s[q]);
  }
  __syncthreads();
  for (int lin = tid; lin < 16 * 64; lin += 256) {
    int h = lin >> 6, q = lin & 63;
    tTbf[((size_t)b * H + h0 + h) * QL + q0 + q] = lds[h * 66 + q];
  }
}

// q-index swizzle inside Ps rows: spreads transposed writes across banks,
// preserves 8-element contiguity; (q,q+1) stay adjacent for even q (b32 packs).
__device__ __forceinline__ int qswz(int q, int c) {
  return q ^ (((c >> 3) & 7) << 3);
}

// ---------------- KBF: recompute score + qmask exp + rsum; dual GEMM + output ----
// grid 1D (CL/32)*B, b innermost; block 256 (4 waves). Plain (non-NT) stores.
__global__ __launch_bounds__(256) void kb_fused(
    const unsigned short* __restrict__ ctxwT, const unsigned short* __restrict__ qryT,
    const unsigned short* __restrict__ qrybf, const unsigned short* __restrict__ tTbf,
    const unsigned short* __restrict__ ctxbf,
    const float* __restrict__ pct, const float* __restrict__ pqt,
    const int* __restrict__ qmask, float* __restrict__ out) {
  __shared__ unsigned short Ps[32 * 264];   // [32 c][264 q], q-swizzled
  __shared__ float stats[32][4];
  const int wg = blockIdx.x;
  const int b = wg & (B - 1);
  const int c0 = (wg >> 4) * 32;
  const int tid = threadIdx.x;
  const int w = tid >> 6, l = tid & 63;
  const int lr = l & 31, hi = l >> 5;
  const int c = c0 + lr;

  // B-frags: ctxwT row c (shared across both q-tiles)
  const unsigned short* bp = ctxwT + ((size_t)b * CL + c) * H + hi * 8;
  bf16x8 bfr[8];
  #pragma unroll
  for (int k = 0; k < 8; ++k) bfr[k] = *(const bf16x8*)(bp + k * 16);

  const float ct = pct[b * CL + c] + pct[B * CL + b * CL + c];

  float rs = 0.f;
  #pragma unroll
  for (int t2 = 0; t2 < 2; ++t2) {
    const int q0 = (2 * w + t2) * 32;
    const unsigned short* ap = qryT + ((size_t)b * QL + q0 + lr) * H + hi * 8;
    f32x16 acc = {};
    #pragma unroll
    for (int k = 0; k < 8; ++k)
      acc = __builtin_amdgcn_mfma_f32_32x32x16_bf16(
          *(const bf16x8*)(ap + k * 16), bfr[k], acc, 0, 0, 0);
    #pragma unroll
    for (int g = 0; g < 4; ++g) {
      const int qbase = q0 + 4 * hi + 8 * g;   // even
      float4 qa = *(const float4*)&pqt[b * QL + qbase];
      float4 qb = *(const float4*)&pqt[B * QL + b * QL + qbase];
      int4 m4 = *(const int4*)&qmask[b * QL + qbase];
      float e0 = m4.x > 0 ? __expf(acc[4*g+0] + ct + qa.x + qb.x - SHIFT) : 0.f;
      float e1 = m4.y > 0 ? __expf(acc[4*g+1] + ct + qa.y + qb.y - SHIFT) : 0.f;
      float e2 = m4.z > 0 ? __expf(acc[4*g+2] + ct + qa.z + qb.z - SHIFT) : 0.f;
      float e3 = m4.w > 0 ? __expf(acc[4*g+3] + ct + qa.w + qb.w - SHIFT) : 0.f;
      rs += e0 + e1 + e2 + e3;
      const unsigned v01 = (unsigned)f2bf(e0) | ((unsigned)f2bf(e1) << 16);
      const unsigned v23 = (unsigned)f2bf(e2) | ((unsigned)f2bf(e3) << 16);
      *(unsigned*)&Ps[lr * 264 + qswz(qbase, lr)] = v01;
      *(unsigned*)&Ps[lr * 264 + qswz(qbase + 2, lr)] = v23;
    }
  }
  rs += __shfl_xor(rs, 32);
  if (hi == 0) stats[lr][w] = rs;

  // hoist epilogue ctx values (overlap with staging)
  const int h0 = w * 32;
  unsigned short cvu[16];
  {
    const unsigned short* cvp = ctxbf + (size_t)b * H * CL + c;
    #pragma unroll
    for (int r = 0; r < 16; ++r) {
      const int h = h0 + (r & 3) + 8 * (r >> 2) + 4 * hi;
      cvu[r] = cvp[(size_t)h * CL];
    }
  }
  __syncthreads();
  const float rinv = 1.0f / (stats[lr][0] + stats[lr][1] + stats[lr][2] + stats[lr][3]);

  // dual GEMM in groups of 4 kc: issue 12 frags, fence, then 8 MFMAs (setprio).
  const unsigned short* a1p = qrybf + ((size_t)b * H + h0 + lr) * QL + hi * 8;
  const unsigned short* a2p = tTbf + ((size_t)b * H + h0 + lr) * QL + hi * 8;
  f32x16 accA = {}, accB = {};
  #pragma unroll
  for (int kg = 0; kg < 4; ++kg) {
    bf16x8 pv[4], a1v[4], a2v[4];
    #pragma unroll
    for (int j = 0; j < 4; ++j) {
      const int kc = kg * 4 + j;
      pv[j]  = *(const bf16x8*)&Ps[lr * 264 + qswz(kc * 16 + hi * 8, lr)];
      a1v[j] = *(const bf16x8*)(a1p + kc * 16);
      a2v[j] = *(const bf16x8*)(a2p + kc * 16);
    }
    __builtin_amdgcn_sched_barrier(0);   // keep all 12 loads issued before MFMAs
    __builtin_amdgcn_s_setprio(1);
    #pragma unroll
    for (int j = 0; j < 4; ++j) {
      accA = __builtin_amdgcn_mfma_f32_32x32x16_bf16(a1v[j], pv[j], accA, 0, 0, 0);
      accB = __builtin_amdgcn_mfma_f32_32x32x16_bf16(a2v[j], pv[j], accB, 0, 0, 0);
    }
    __builtin_amdgcn_s_setprio(0);
  }
  float* ob = out + (size_t)b * 4 * H * CL;
  #pragma unroll
  for (int r = 0; r < 16; ++r) {
    const int h = h0 + (r & 3) + 8 * (r >> 2) + 4 * hi;
    const float cv = bf2f(cvu[r]);
    const float av = accA[r] * rinv;
    const float bv = accB[r] * rinv;
    ob[(size_t)(H + h) * CL + c] = av;
    ob[(size_t)(2 * H + h) * CL + c] = cv * av;
    ob[(size_t)(3 * H + h) * CL + c] = cv * bv;
  }
}

extern "C" void kernel_launch(void* const* d_in, const int* in_sizes, int n_in,
                              void* d_out, int out_size, void* d_ws, size_t ws_size,
                              hipStream_t stream) {
  const float* context  = (const float*)d_in[0];
  const float* question = (const float*)d_in[1];
  const int*   c_mask   = (const int*)d_in[2];
  const int*   q_mask   = (const int*)d_in[3];
  const float* w        = (const float*)d_in[4];
  float* out = (float*)d_out;

  char* ws = (char*)d_ws;
  size_t off = 0;
  auto alloc = [&](size_t bytes) -> void* {
    void* p = ws + off;
    off += (bytes + 255) & ~(size_t)255;
    return p;
  };
  unsigned short* ctx_bf = (unsigned short*)alloc((size_t)B * H * CL * 2);    // 8.4 MB
  unsigned short* ctxwT  = (unsigned short*)alloc((size_t)B * CL * H * 2);    // 8.4 MB
  unsigned short* qry_bf = (unsigned short*)alloc((size_t)B * H * QL * 2);    // 1.05 MB
  unsigned short* qryT   = (unsigned short*)alloc((size_t)B * QL * H * 2);    // 1.05 MB
  unsigned short* tpart  = (unsigned short*)alloc((size_t)SPLITK5 * B * QL * H * 2); // 4.2 MB
  unsigned short* tT_bf  = (unsigned short*)alloc((size_t)B * H * QL * 2);    // 1.05 MB
  float* pct   = (float*)alloc((size_t)2 * B * CL * sizeof(float));
  float* pqt   = (float*)alloc((size_t)2 * B * QL * sizeof(float));
  float* Lpart = (float*)alloc((size_t)B * SPLITK5 * QL * sizeof(float));

  ktrans_all<<<dim3(CL / 64 + QL / 64, H / 64, B), dim3(256), 0, stream>>>(
      context, question, w, ctx_bf, ctxwT, qry_bf, qryT, pct, pqt, out);

  k5_fused<<<dim3((QL / 32) * SPLITK5 * B), dim3(256), 0, stream>>>(
      ctxwT, qryT, ctx_bf, pct, pqt, c_mask, tpart, Lpart);

  k5b_treduce<<<dim3(QL / 64, H / 16, B), dim3(256), 0, stream>>>(
      tpart, Lpart, tT_bf);

  kb_fused<<<dim3((CL / 32) * B), dim3(256), 0, stream>>>(
      ctxwT, qryT, qry_bf, tT_bf, ctx_bf, pct, pqt, q_mask, out);
}

// Round 30
// 72.831 us; speedup vs baseline: 1.0365x; 1.0365x over previous
//
#include <hip/hip_runtime.h>

typedef short bf16x8 __attribute__((ext_vector_type(8)));   // 8 bf16 = 4 VGPRs
typedef float f32x16 __attribute__((ext_vector_type(16)));  // MFMA 32x32 acc
typedef float f32x4  __attribute__((ext_vector_type(4)));

constexpr int B  = 16;
constexpr int H  = 128;
constexpr int CL = 2048;
constexpr int QL = 256;
constexpr int SPLITK5 = 4;
constexpr int K5SEG = CL / SPLITK5;   // 512
constexpr int PSTR = K5SEG + 8;       // 520 shorts = 260 dwords === 4 mod 32
constexpr float SHIFT = 8.0f;         // exp shift (overflow-safe, |s| ~ O(6))

__device__ __forceinline__ unsigned short f2bf(float x) {
  unsigned u = __float_as_uint(x);
  u += 0x7fffu + ((u >> 16) & 1u);   // round-to-nearest-even
  return (unsigned short)(u >> 16);
}
__device__ __forceinline__ float bf2f(unsigned short u) {
  return __uint_as_float((unsigned)u << 16);
}

// fragment-major pack index for 32x32x16 A-operand over [128 h][256 q]:
// element (h,q) -> [b][h>>5][q>>4][(h&31)+((q>>3)&1)*32][q&7]
__device__ __forceinline__ size_t packA(int b, int h, int q) {
  return ((((size_t)b * 4 + (h >> 5)) * 16 + (q >> 4)) * 64
          + (h & 31) + (((q >> 3) & 1) << 5)) * 8 + (q & 7);
}

// ---------------- KT: fp32 -> bf16 linear + transposed copies + bias partials ----
// ctx path additionally writes output group 0 (exact fp32 copy, NT stores).
// qry path writes the linear copy in fragment-major (packed) layout for kb.
template<int L, bool SCALE, bool WOUT, bool PACKQ>
__device__ __forceinline__ void ktrans_body(
    const float* __restrict__ src, const float* __restrict__ wbias,
    const float* __restrict__ wscale,
    unsigned short* __restrict__ dlin, unsigned short* __restrict__ dT,
    float* __restrict__ pbias, float* __restrict__ outg0,
    int bxl, int h1, int b, int tid,
    unsigned short (*T)[72], float (*P)[64]) {
  const int c0 = bxl * 64;
  const int hh = tid >> 4;
  const int cc4 = (tid & 15) * 4;
  float4 part = make_float4(0.f, 0.f, 0.f, 0.f);
  #pragma unroll
  for (int it = 0; it < 4; ++it) {
    const int hrow = it * 16 + hh;
    const int h = h1 * 64 + hrow;
    float4 v = *(const float4*)&src[((size_t)b * H + h) * L + c0 + cc4];
    const float wb = wbias[h];
    part.x = fmaf(v.x, wb, part.x); part.y = fmaf(v.y, wb, part.y);
    part.z = fmaf(v.z, wb, part.z); part.w = fmaf(v.w, wb, part.w);
    if (WOUT) {
      f32x4 t;
      t[0] = v.x; t[1] = v.y; t[2] = v.z; t[3] = v.w;
      __builtin_nontemporal_store(
          t, (f32x4*)&outg0[((size_t)b * 4 * H + h) * (size_t)CL + c0 + cc4]);
    }
    ushort4 o;
    o.x = f2bf(v.x); o.y = f2bf(v.y); o.z = f2bf(v.z); o.w = f2bf(v.w);
    if (PACKQ) {
      const int q0i = c0 + cc4;            // (q0i&7) in {0,4}: 8B-aligned ushort4
      *(ushort4*)&dlin[packA(b, h, q0i)] = o;
    } else {
      *(ushort4*)&dlin[((size_t)b * H + h) * L + c0 + cc4] = o;
    }
    ushort4 ot;
    if (SCALE) {
      const float ws = wscale[h];
      ot.x = f2bf(v.x * ws); ot.y = f2bf(v.y * ws);
      ot.z = f2bf(v.z * ws); ot.w = f2bf(v.w * ws);
    } else {
      ot = o;
    }
    *(ushort4*)&T[hrow][cc4] = ot;
  }
  *(float4*)&P[hh][cc4] = part;
  __syncthreads();
  if (tid < 64) {
    float sum = 0.f;
    #pragma unroll
    for (int i = 0; i < 16; ++i) sum += P[i][tid];
    pbias[(size_t)h1 * B * L + (size_t)b * L + c0 + tid] = sum;
  }
  #pragma unroll
  for (int it = 0; it < 4; ++it) {
    int lin = it * 256 + tid;
    int c = lin >> 4, hc = (lin & 15) * 4;
    ushort4 o;
    o.x = T[hc + 0][c]; o.y = T[hc + 1][c];
    o.z = T[hc + 2][c]; o.w = T[hc + 3][c];
    *(ushort4*)&dT[((size_t)b * L + c0 + c) * H + h1 * 64 + hc] = o;
  }
}

__global__ __launch_bounds__(256) void ktrans_all(
    const float* __restrict__ ctx, const float* __restrict__ qry,
    const float* __restrict__ w,
    unsigned short* __restrict__ ctx_bf, unsigned short* __restrict__ ctxwT,
    unsigned short* __restrict__ qry_pq, unsigned short* __restrict__ qryT,
    float* __restrict__ pct, float* __restrict__ pqt,
    float* __restrict__ out) {
  __shared__ unsigned short T[64][72];
  __shared__ float P[16][64];
  const int h1 = blockIdx.y, b = blockIdx.z, tid = threadIdx.x;
  const int bx = blockIdx.x;
  if (bx < CL / 64) {
    ktrans_body<CL, true, true, false>(ctx, w + H, w + 2 * H, ctx_bf, ctxwT,
                                       pct, out, bx, h1, b, tid, T, P);
  } else {
    ktrans_body<QL, false, false, true>(qry, w, w, qry_pq, qryT, pqt, nullptr,
                                        bx - CL / 64, h1, b, tid, T, P);
  }
}

// ---------------- K5F: recompute score + cmask exp -> LDS P; t-MFMA + Lpart ----
// grid 1D = (QL/32)*SPLITK5*B, b innermost. block 256.
__global__ __launch_bounds__(256) void k5_fused(
    const unsigned short* __restrict__ ctxwT, const unsigned short* __restrict__ qryT,
    const unsigned short* __restrict__ ctxbf,
    const float* __restrict__ pct, const float* __restrict__ pqt,
    const int* __restrict__ cmask,
    unsigned short* __restrict__ tpart, float* __restrict__ Lpart) {
  __shared__ unsigned short P[32 * PSTR];  // [32 q][520 c], c XOR-swizzled per q-oct
  const int wg = blockIdx.x;
  const int b = wg & (B - 1);
  const int seg = (wg >> 4) & (SPLITK5 - 1);
  const int q0 = (wg >> 6) * 32;
  const int cseg = seg * K5SEG;
  const int tid = threadIdx.x;
  const int w = tid >> 6, l = tid & 63;
  const int lr = l & 31, hi = l >> 5;

  // A-frags: qryT rows q0+lr (shared across all four c-tiles)
  const unsigned short* ap = qryT + ((size_t)b * QL + q0 + lr) * H + hi * 8;
  bf16x8 afr[8];
  #pragma unroll
  for (int k = 0; k < 8; ++k) afr[k] = *(const bf16x8*)(ap + k * 16);

  #pragma unroll
  for (int t4 = 0; t4 < 4; ++t4) {
    const int cl = w * 128 + t4 * 32 + lr;  // local c in [0,512)
    const int c = cseg + cl;
    const unsigned short* bp = ctxwT + ((size_t)b * CL + c) * H + hi * 8;
    f32x16 acc = {};
    #pragma unroll
    for (int k = 0; k < 8; ++k) {
      bf16x8 bfr = *(const bf16x8*)(bp + k * 16);
      acc = __builtin_amdgcn_mfma_f32_32x32x16_bf16(afr[k], bfr, acc, 0, 0, 0);
    }
    const float ct = pct[b * CL + c] + pct[B * CL + b * CL + c];
    const bool cm = cmask[b * CL + c] > 0;
    #pragma unroll
    for (int g = 0; g < 4; ++g) {
      const int ql = 4 * hi + 8 * g;        // local q row
      const int qbase = q0 + ql;
      float4 qa = *(const float4*)&pqt[b * QL + qbase];
      float4 qb = *(const float4*)&pqt[B * QL + b * QL + qbase];
      const int key = (g & 3) << 3;         // ((ql>>3)&3)<<3
      const int cs = cl ^ key;
      P[(ql + 0) * PSTR + cs] = f2bf(cm ? __expf(acc[4*g+0] + ct + qa.x + qb.x - SHIFT) : 0.f);
      P[(ql + 1) * PSTR + cs] = f2bf(cm ? __expf(acc[4*g+1] + ct + qa.y + qb.y - SHIFT) : 0.f);
      P[(ql + 2) * PSTR + cs] = f2bf(cm ? __expf(acc[4*g+2] + ct + qa.z + qb.z - SHIFT) : 0.f);
      P[(ql + 3) * PSTR + cs] = f2bf(cm ? __expf(acc[4*g+3] + ct + qa.w + qb.w - SHIFT) : 0.f);
    }
  }
  __syncthreads();

  // t phase: wave w owns h-tile w. A = P rows (q=lr, swizzled), B = ctx_bf rows h.
  // Groups of 4 kc: issue 8 frags, fence (sched_barrier), then 4 MFMAs (setprio).
  const int h0 = w * 32;
  const unsigned short* bp2 = ctxbf + ((size_t)b * H + h0 + lr) * CL + cseg + hi * 8;
  const int rkey = ((lr >> 3) & 3) << 3;
  f32x16 acc = {};
  #pragma unroll
  for (int kg = 0; kg < 8; ++kg) {
    bf16x8 av[4], bv[4];
    #pragma unroll
    for (int j = 0; j < 4; ++j) {
      const int kc = kg * 4 + j;
      av[j] = *(const bf16x8*)&P[lr * PSTR + ((kc * 16 + hi * 8) ^ rkey)];
      bv[j] = *(const bf16x8*)(bp2 + kc * 16);
    }
    __builtin_amdgcn_sched_barrier(0);   // keep all 8 loads issued before MFMAs
    __builtin_amdgcn_s_setprio(1);
    #pragma unroll
    for (int j = 0; j < 4; ++j)
      acc = __builtin_amdgcn_mfma_f32_32x32x16_bf16(av[j], bv[j], acc, 0, 0, 0);
    __builtin_amdgcn_s_setprio(0);
  }
  unsigned short* tp = tpart + (size_t)(seg * B + b) * QL * H;
  #pragma unroll
  for (int r = 0; r < 16; ++r) {
    int qrow = (r & 3) + 8 * (r >> 2) + 4 * hi;
    tp[(size_t)(q0 + qrow) * H + h0 + lr] = f2bf(acc[r]);
  }

  // Lpart: per-q row sums of P (swizzle is a within-row bijection; sum invariant)
  {
    const int ql = tid >> 3, j = tid & 7;
    const unsigned short* pr = &P[ql * PSTR + j * 64];
    float s = 0.f;
    #pragma unroll
    for (int k = 0; k < 8; ++k) {
      bf16x8 v = *(const bf16x8*)(pr + k * 8);
      #pragma unroll
      for (int i = 0; i < 8; ++i) s += bf2f((unsigned short)v[i]);
    }
    s += __shfl_xor(s, 1);
    s += __shfl_xor(s, 2);
    s += __shfl_xor(s, 4);
    if (j == 0) Lpart[((size_t)b * SPLITK5 + seg) * QL + q0 + ql] = s;
  }
}

// ---------------- K5b: cinv from Lpart + reduce tpart; write tT PACKED ----
// grid (QL/64, H/16, B) = 512 blocks.
__global__ __launch_bounds__(256) void k5b_treduce(
    const unsigned short* __restrict__ tpart, const float* __restrict__ Lpart,
    unsigned short* __restrict__ tT_pq) {
  __shared__ unsigned short lds[16 * 66];
  __shared__ float cinv_s[64];
  const int q0 = blockIdx.x * 64, h0 = blockIdx.y * 16, b = blockIdx.z;
  const int tid = threadIdx.x;
  if (tid < 64) {
    float Ls = 0.f;
    #pragma unroll
    for (int s = 0; s < SPLITK5; ++s)
      Ls += Lpart[((size_t)b * SPLITK5 + s) * QL + q0 + tid];
    cinv_s[tid] = 1.0f / Ls;
  }
  __syncthreads();
  for (int lin = tid; lin < 64 * 16; lin += 256) {
    int q = lin >> 4, h = lin & 15;
    float v = 0.f;
    #pragma unroll
    for (int sgt = 0; sgt < SPLITK5; ++sgt)
      v += bf2f(tpart[((size_t)(sgt * B + b) * QL + q0 + q) * H + h0 + h]);
    lds[h * 66 + q] = f2bf(v * cinv_s[q]);
  }
  __syncthreads();
  for (int lin = tid; lin < 16 * 64; lin += 256) {
    int h = lin >> 6, q = lin & 63;
    tT_pq[packA(b, h0 + h, q0 + q)] = lds[h * 66 + q];
  }
}

// q-index swizzle inside Ps rows: spreads transposed writes across banks,
// preserves 8-element contiguity; (q,q+1) stay adjacent for even q (b32 packs).
__device__ __forceinline__ int qswz(int q, int c) {
  return q ^ (((c >> 3) & 7) << 3);
}

// ---------------- KBF: recompute score + qmask exp + rsum; dual GEMM + output ----
// grid 1D (CL/32)*B, b innermost; block 256 (4 waves). Plain (non-NT) stores.
// GEMM A-operands read from fragment-major packed buffers (coalesced waves).
__global__ __launch_bounds__(256) void kb_fused(
    const unsigned short* __restrict__ ctxwT, const unsigned short* __restrict__ qryT,
    const unsigned short* __restrict__ qry_pq, const unsigned short* __restrict__ tT_pq,
    const unsigned short* __restrict__ ctxbf,
    const float* __restrict__ pct, const float* __restrict__ pqt,
    const int* __restrict__ qmask, float* __restrict__ out) {
  __shared__ unsigned short Ps[32 * 264];   // [32 c][264 q], q-swizzled
  __shared__ float stats[32][4];
  const int wg = blockIdx.x;
  const int b = wg & (B - 1);
  const int c0 = (wg >> 4) * 32;
  const int tid = threadIdx.x;
  const int w = tid >> 6, l = tid & 63;
  const int lr = l & 31, hi = l >> 5;
  const int c = c0 + lr;

  // B-frags: ctxwT row c (shared across both q-tiles)
  const unsigned short* bp = ctxwT + ((size_t)b * CL + c) * H + hi * 8;
  bf16x8 bfr[8];
  #pragma unroll
  for (int k = 0; k < 8; ++k) bfr[k] = *(const bf16x8*)(bp + k * 16);

  const float ct = pct[b * CL + c] + pct[B * CL + b * CL + c];

  float rs = 0.f;
  #pragma unroll
  for (int t2 = 0; t2 < 2; ++t2) {
    const int q0 = (2 * w + t2) * 32;
    const unsigned short* ap = qryT + ((size_t)b * QL + q0 + lr) * H + hi * 8;
    f32x16 acc = {};
    #pragma unroll
    for (int k = 0; k < 8; ++k)
      acc = __builtin_amdgcn_mfma_f32_32x32x16_bf16(
          *(const bf16x8*)(ap + k * 16), bfr[k], acc, 0, 0, 0);
    #pragma unroll
    for (int g = 0; g < 4; ++g) {
      const int qbase = q0 + 4 * hi + 8 * g;   // even
      float4 qa = *(const float4*)&pqt[b * QL + qbase];
      float4 qb = *(const float4*)&pqt[B * QL + b * QL + qbase];
      int4 m4 = *(const int4*)&qmask[b * QL + qbase];
      float e0 = m4.x > 0 ? __expf(acc[4*g+0] + ct + qa.x + qb.x - SHIFT) : 0.f;
      float e1 = m4.y > 0 ? __expf(acc[4*g+1] + ct + qa.y + qb.y - SHIFT) : 0.f;
      float e2 = m4.z > 0 ? __expf(acc[4*g+2] + ct + qa.z + qb.z - SHIFT) : 0.f;
      float e3 = m4.w > 0 ? __expf(acc[4*g+3] + ct + qa.w + qb.w - SHIFT) : 0.f;
      rs += e0 + e1 + e2 + e3;
      const unsigned v01 = (unsigned)f2bf(e0) | ((unsigned)f2bf(e1) << 16);
      const unsigned v23 = (unsigned)f2bf(e2) | ((unsigned)f2bf(e3) << 16);
      *(unsigned*)&Ps[lr * 264 + qswz(qbase, lr)] = v01;
      *(unsigned*)&Ps[lr * 264 + qswz(qbase + 2, lr)] = v23;
    }
  }
  rs += __shfl_xor(rs, 32);
  if (hi == 0) stats[lr][w] = rs;

  // hoist epilogue ctx values (overlap with staging)
  const int h0 = w * 32;
  unsigned short cvu[16];
  {
    const unsigned short* cvp = ctxbf + (size_t)b * H * CL + c;
    #pragma unroll
    for (int r = 0; r < 16; ++r) {
      const int h = h0 + (r & 3) + 8 * (r >> 2) + 4 * hi;
      cvu[r] = cvp[(size_t)h * CL];
    }
  }
  __syncthreads();
  const float rinv = 1.0f / (stats[lr][0] + stats[lr][1] + stats[lr][2] + stats[lr][3]);

  // dual GEMM in groups of 4 kc. Packed A-frags: wave reads 1KB contiguous.
  const unsigned short* a1p = qry_pq + (((size_t)b * 4 + w) * 16) * 512 + (size_t)l * 8;
  const unsigned short* a2p = tT_pq + (((size_t)b * 4 + w) * 16) * 512 + (size_t)l * 8;
  f32x16 accA = {}, accB = {};
  #pragma unroll
  for (int kg = 0; kg < 4; ++kg) {
    bf16x8 pv[4], a1v[4], a2v[4];
    #pragma unroll
    for (int j = 0; j < 4; ++j) {
      const int kc = kg * 4 + j;
      pv[j]  = *(const bf16x8*)&Ps[lr * 264 + qswz(kc * 16 + hi * 8, lr)];
      a1v[j] = *(const bf16x8*)(a1p + (size_t)kc * 512);
      a2v[j] = *(const bf16x8*)(a2p + (size_t)kc * 512);
    }
    __builtin_amdgcn_sched_barrier(0);   // keep all 12 loads issued before MFMAs
    __builtin_amdgcn_s_setprio(1);
    #pragma unroll
    for (int j = 0; j < 4; ++j) {
      accA = __builtin_amdgcn_mfma_f32_32x32x16_bf16(a1v[j], pv[j], accA, 0, 0, 0);
      accB = __builtin_amdgcn_mfma_f32_32x32x16_bf16(a2v[j], pv[j], accB, 0, 0, 0);
    }
    __builtin_amdgcn_s_setprio(0);
  }
  float* ob = out + (size_t)b * 4 * H * CL;
  #pragma unroll
  for (int r = 0; r < 16; ++r) {
    const int h = h0 + (r & 3) + 8 * (r >> 2) + 4 * hi;
    const float cv = bf2f(cvu[r]);
    const float av = accA[r] * rinv;
    const float bv = accB[r] * rinv;
    ob[(size_t)(H + h) * CL + c] = av;
    ob[(size_t)(2 * H + h) * CL + c] = cv * av;
    ob[(size_t)(3 * H + h) * CL + c] = cv * bv;
  }
}

extern "C" void kernel_launch(void* const* d_in, const int* in_sizes, int n_in,
                              void* d_out, int out_size, void* d_ws, size_t ws_size,
                              hipStream_t stream) {
  const float* context  = (const float*)d_in[0];
  const float* question = (const float*)d_in[1];
  const int*   c_mask   = (const int*)d_in[2];
  const int*   q_mask   = (const int*)d_in[3];
  const float* w        = (const float*)d_in[4];
  float* out = (float*)d_out;

  char* ws = (char*)d_ws;
  size_t off = 0;
  auto alloc = [&](size_t bytes) -> void* {
    void* p = ws + off;
    off += (bytes + 255) & ~(size_t)255;
    return p;
  };
  unsigned short* ctx_bf = (unsigned short*)alloc((size_t)B * H * CL * 2);    // 8.4 MB
  unsigned short* ctxwT  = (unsigned short*)alloc((size_t)B * CL * H * 2);    // 8.4 MB
  unsigned short* qry_pq = (unsigned short*)alloc((size_t)B * H * QL * 2);    // 1.05 MB packed
  unsigned short* qryT   = (unsigned short*)alloc((size_t)B * QL * H * 2);    // 1.05 MB
  unsigned short* tpart  = (unsigned short*)alloc((size_t)SPLITK5 * B * QL * H * 2); // 4.2 MB
  unsigned short* tT_pq  = (unsigned short*)alloc((size_t)B * H * QL * 2);    // 1.05 MB packed
  float* pct   = (float*)alloc((size_t)2 * B * CL * sizeof(float));
  float* pqt   = (float*)alloc((size_t)2 * B * QL * sizeof(float));
  float* Lpart = (float*)alloc((size_t)B * SPLITK5 * QL * sizeof(float));

  ktrans_all<<<dim3(CL / 64 + QL / 64, H / 64, B), dim3(256), 0, stream>>>(
      context, question, w, ctx_bf, ctxwT, qry_pq, qryT, pct, pqt, out);

  k5_fused<<<dim3((QL / 32) * SPLITK5 * B), dim3(256), 0, stream>>>(
      ctxwT, qryT, ctx_bf, pct, pqt, c_mask, tpart, Lpart);

  k5b_treduce<<<dim3(QL / 64, H / 16, B), dim3(256), 0, stream>>>(
      tpart, Lpart, tT_pq);

  kb_fused<<<dim3((CL / 32) * B), dim3(256), 0, stream>>>(
      ctxwT, qryT, qry_pq, tT_pq, ctx_bf, pct, pqt, q_mask, out);
}